// Round 8
// baseline (390.943 us; speedup 1.0000x reference)
//
#include <hip/hip_runtime.h>

typedef short s16x8 __attribute__((ext_vector_type(8)));
typedef short s16x4 __attribute__((ext_vector_type(4)));
typedef float f32x4 __attribute__((ext_vector_type(4)));
typedef unsigned short u16;
typedef unsigned int u32;

#define MFMA16(a, b, c) __builtin_amdgcn_mfma_f32_16x16x32_bf16((a), (b), (c), 0, 0, 0)
#define MFMA1616(a, b, c) __builtin_amdgcn_mfma_f32_16x16x16bf16_1k((a), (b), (c), 0, 0, 0)

__device__ __forceinline__ u16 f2bf(float f) {
  u32 u = __float_as_uint(f);
  u += 0x7fffu + ((u >> 16) & 1u);
  return (u16)(u >> 16);
}
__device__ __forceinline__ u16 f2bf_fast(float f) {
  return (u16)((__float_as_uint(f) + 0x8000u) >> 16);
}
__device__ __forceinline__ float bf2f(u16 u) {
  return __uint_as_float(((u32)u) << 16);
}
__device__ __forceinline__ float ex2(float x) {
  float r;
  asm("v_exp_f32 %0, %1" : "=v"(r) : "v"(x));
  return r;
}
__device__ __forceinline__ void gll(const u16* g, u16* l) {
  __builtin_amdgcn_global_load_lds((const __attribute__((address_space(1))) u32*)g,
                                   (__attribute__((address_space(3))) u32*)l, 16, 0, 0);
}

// ---------------- fused prep: x->bf16, W^T->bf16 (LDS tile transpose) ----------------
__global__ __launch_bounds__(256) void k_prep(const float* __restrict__ x,
                                              const float* __restrict__ Wq,
                                              const float* __restrict__ Wkv,
                                              const float* __restrict__ Wo,
                                              u16* __restrict__ xb,
                                              u16* __restrict__ wqkvt,
                                              u16* __restrict__ wot) {
  const int bx = blockIdx.x, t = threadIdx.x;
  if (bx < 4096) {
    int i = bx * 256 + t;
    float4 v = ((const float4*)x)[i];
    ushort4 o;
    o.x = f2bf(v.x); o.y = f2bf(v.y); o.z = f2bf(v.z); o.w = f2bf(v.w);
    ((ushort4*)xb)[i] = o;
    return;
  }
  __shared__ u16 tl[64 * 66];
  const float* src; u16* dst; int N, kb, nb;
  if (bx < 4160)      { int tb = bx - 4096; src = Wq;  dst = wqkvt;          N = 512;  kb = tb >> 3; nb = tb & 7; }
  else if (bx < 4288) { int tb = bx - 4160; src = Wkv; dst = wqkvt + 262144; N = 1024; kb = tb >> 4; nb = tb & 15; }
  else                { int tb = bx - 4288; src = Wo;  dst = wot;            N = 512;  kb = tb >> 3; nb = tb & 7; }
#pragma unroll
  for (int it = 0; it < 4; ++it) {
    int idx = it * 256 + t;
    int kl = idx >> 4, nc = idx & 15;
    float4 v = *(const float4*)(src + (kb * 64 + kl) * N + nb * 64 + nc * 4);
    u16* p = &tl[kl * 66 + nc * 4];
    p[0] = f2bf(v.x); p[1] = f2bf(v.y); p[2] = f2bf(v.z); p[3] = f2bf(v.w);
  }
  __syncthreads();
#pragma unroll
  for (int it = 0; it < 2; ++it) {
    int idx = it * 256 + t;
    int nl = idx >> 3, kc = idx & 7;
    u16 tmp[8];
#pragma unroll
    for (int j = 0; j < 8; ++j) tmp[j] = tl[(kc * 8 + j) * 66 + nl];
    *(s16x8*)(dst + (nb * 64 + nl) * 512 + kb * 64 + kc * 8) = *(const s16x8*)tmp;
  }
}

// ---------------- QKV projection GEMM: 128x128 tile, BK=64, async swizzled staging ----------------
// Q/K row-major [bh][n][64]; V in PV-tiled layout [bh][jt][nt][dt][row16=d%16][k16=n%16]
__global__ __launch_bounds__(256, 2) void k_gemm_qkv(
    const u16* __restrict__ A, const u16* __restrict__ Bt,
    u16* __restrict__ Qb, u16* __restrict__ Kb, u16* __restrict__ Vg) {
  __shared__ __align__(16) u16 As[8192], Bs[8192];
  const int t = threadIdx.x, w = t >> 6, l = t & 63, quad = l >> 4, lr = l & 15;
  const int bm = blockIdx.x, bn = blockIdx.y;
  const int wm = (w >> 1) * 64, wn = (w & 1) * 64;
  const f32x4 fz = {0.f, 0.f, 0.f, 0.f};
  f32x4 acc[4][4];
#pragma unroll
  for (int i = 0; i < 4; ++i)
#pragma unroll
    for (int j = 0; j < 4; ++j) acc[i][j] = fz;
  const u16* Ag = A + bm * 128 * 512;
  const u16* Bg = Bt + bn * 128 * 512;
  for (int kk = 0; kk < 8; ++kk) {
    __syncthreads();
#pragma unroll
    for (int i = 0; i < 4; ++i) {
      int ci = w * 256 + i * 64 + l;
      int row = ci >> 3, cb = ci & 7;
      int off = row * 512 + kk * 64 + ((cb ^ (row & 7)) << 3);
      gll(Ag + off, &As[w * 2048 + i * 512]);
      gll(Bg + off, &Bs[w * 2048 + i * 512]);
    }
    __syncthreads();
    s16x8 af[4][2], bf[4][2];
#pragma unroll
    for (int x2 = 0; x2 < 4; ++x2)
#pragma unroll
      for (int c = 0; c < 2; ++c) {
        int sw = ((c * 4 + quad) ^ (lr & 7)) << 3;
        af[x2][c] = *(const s16x8*)&As[(wm + x2 * 16 + lr) * 64 + sw];
        bf[x2][c] = *(const s16x8*)&Bs[(wn + x2 * 16 + lr) * 64 + sw];
      }
#pragma unroll
    for (int c = 0; c < 2; ++c)
#pragma unroll
      for (int ti = 0; ti < 4; ++ti)
#pragma unroll
        for (int tj = 0; tj < 4; ++tj)
          acc[ti][tj] = MFMA16(af[ti][c], bf[tj][c], acc[ti][tj]);
  }
  const int buf = (bn * 128) >> 9;  // uniform: 0=Q,1=K,2=V
  const float QS = 0.0225421107f;   // log2(e)/64
#pragma unroll
  for (int ti = 0; ti < 4; ++ti)
#pragma unroll
    for (int tj = 0; tj < 4; ++tj) {
      int col = bn * 128 + wn + tj * 16 + lr;
      int hd = col & 511, h = hd >> 6, d = hd & 63;
      int row0 = bm * 128 + wm + ti * 16 + quad * 4;
      int b = row0 >> 12, n0 = row0 & 4095;
      long base = (long)(b * 8 + h) * 262144;
      if (buf == 0) {
#pragma unroll
        for (int r = 0; r < 4; ++r) Qb[base + (long)(n0 + r) * 64 + d] = f2bf(acc[ti][tj][r] * QS);
      } else if (buf == 1) {
#pragma unroll
        for (int r = 0; r < 4; ++r) Kb[base + (long)(n0 + r) * 64 + d] = f2bf(acc[ti][tj][r]);
      } else {
        ushort4 pk;
        pk.x = f2bf(acc[ti][tj][0]); pk.y = f2bf(acc[ti][tj][1]);
        pk.z = f2bf(acc[ti][tj][2]); pk.w = f2bf(acc[ti][tj][3]);
        // tiled: offset = ((jt*4+nt)*4+dt)*256 + (d%16)*16 + (n%16); r contiguous in k
        long vaddr = base + ((long)((n0 >> 6) * 4 + ((n0 >> 4) & 3)) * 4 + (d >> 4)) * 256
                     + (long)(d & 15) * 16 + (n0 & 15);
        *(ushort4*)&Vg[vaddr] = pk;
      }
    }
}

// ---------------- output projection GEMM (+bias, fp32 out) ----------------
__global__ __launch_bounds__(256, 2) void k_gemm_out(
    const u16* __restrict__ A, const u16* __restrict__ Bt,
    const float* __restrict__ bias, float* __restrict__ out) {
  __shared__ __align__(16) u16 As[8192], Bs[8192];
  const int t = threadIdx.x, w = t >> 6, l = t & 63, quad = l >> 4, lr = l & 15;
  const int bm = blockIdx.x, bn = blockIdx.y;
  const int wm = (w >> 1) * 64, wn = (w & 1) * 64;
  const f32x4 fz = {0.f, 0.f, 0.f, 0.f};
  f32x4 acc[4][4];
#pragma unroll
  for (int i = 0; i < 4; ++i)
#pragma unroll
    for (int j = 0; j < 4; ++j) acc[i][j] = fz;
  const u16* Ag = A + bm * 128 * 512;
  const u16* Bg = Bt + bn * 128 * 512;
  for (int kk = 0; kk < 8; ++kk) {
    __syncthreads();
#pragma unroll
    for (int i = 0; i < 4; ++i) {
      int ci = w * 256 + i * 64 + l;
      int row = ci >> 3, cb = ci & 7;
      int off = row * 512 + kk * 64 + ((cb ^ (row & 7)) << 3);
      gll(Ag + off, &As[w * 2048 + i * 512]);
      gll(Bg + off, &Bs[w * 2048 + i * 512]);
    }
    __syncthreads();
    s16x8 af[4][2], bf[4][2];
#pragma unroll
    for (int x2 = 0; x2 < 4; ++x2)
#pragma unroll
      for (int c = 0; c < 2; ++c) {
        int sw = ((c * 4 + quad) ^ (lr & 7)) << 3;
        af[x2][c] = *(const s16x8*)&As[(wm + x2 * 16 + lr) * 64 + sw];
        bf[x2][c] = *(const s16x8*)&Bs[(wn + x2 * 16 + lr) * 64 + sw];
      }
#pragma unroll
    for (int c = 0; c < 2; ++c)
#pragma unroll
      for (int ti = 0; ti < 4; ++ti)
#pragma unroll
        for (int tj = 0; tj < 4; ++tj)
          acc[ti][tj] = MFMA16(af[ti][c], bf[tj][c], acc[ti][tj]);
  }
#pragma unroll
  for (int ti = 0; ti < 4; ++ti)
#pragma unroll
    for (int tj = 0; tj < 4; ++tj) {
      int col = bn * 128 + wn + tj * 16 + lr;
      float bb = bias[col];
#pragma unroll
      for (int r = 0; r < 4; ++r) {
        int row = bm * 128 + wm + ti * 16 + quad * 4 + r;
        out[(long)row * 512 + col] = acc[ti][tj][r] + bb;
      }
    }
}

// ---------------- K-split flash attention, S^T engine, register-direct V ----------------
// grid 4096 = (64 qt desc) x (16 bh) x (4 c); 128 thr = 2 waves x 32 q-rows.
// S^T = K·Q^T; softmax row m = lane&15 (in-lane max + 2 shuffles); P^T stays in
// registers (B-operand of 16x16x16). V fragments load straight global->VGPR
// (per (nt,dt) the wave covers one contiguous 512B segment; L2-resident) —
// no V staging, no V ds_reads, no V bank conflicts. LDS 8KB = K only.
__global__ __launch_bounds__(128, 4) void k_attn_split(
    const u16* __restrict__ Qb, const u16* __restrict__ Kb,
    const u16* __restrict__ Vg, u16* __restrict__ pO,
    float* __restrict__ pM, float* __restrict__ pL) {
  const int bid = blockIdx.x;
  const int qt = 63 - (bid >> 6), rem = bid & 63, bh = rem >> 2, c = rem & 3;
  const int jcount = qt + 1;
  const int nc = (jcount + 15) >> 4;
  if (c >= nc) return;  // block-uniform early exit (before any barrier)
  const int jstart = c * 16;
  const int jendx = (jstart + 16 < jcount) ? jstart + 16 : jcount;
  __shared__ __align__(16) u16 lds[4096];  // K tile only
  const int t = threadIdx.x, w = t >> 6, l = t & 63, quad = l >> 4, lr = l & 15;
  const u16* Qh = Qb + (long)bh * 262144;
  const u16* Kh = Kb + (long)bh * 262144;
  const u16* Vh = Vg + (long)bh * 262144;
  const int rw0 = qt * 64 + w * 32;
  s16x8 qf[2][2];
#pragma unroll
  for (int mt = 0; mt < 2; ++mt)
#pragma unroll
    for (int cc = 0; cc < 2; ++cc)
      qf[mt][cc] = *(const s16x8*)(Qh + (rw0 + mt * 16 + lr) * 64 + cc * 32 + quad * 8);
  const f32x4 fz = {0.f, 0.f, 0.f, 0.f};
  f32x4 o[2][4];  // O^T: [mt][dt], C-layout col=m=lr, row=d=quad*4+r
#pragma unroll
  for (int mt = 0; mt < 2; ++mt)
#pragma unroll
    for (int dt = 0; dt < 4; ++dt) o[mt][dt] = fz;
  float m_r[2] = {-3.0e38f, -3.0e38f};
  float lp[2] = {0.f, 0.f};  // per-lane l partials (quad-subset of n)
  const int voff = lr * 16 + quad * 4;  // per-lane V fragment offset within 256-elem tile

  for (int jt = jstart; jt < jendx; ++jt) {
    __syncthreads();  // all waves done reading previous K tile
    const u16* Ksrc = Kh + jt * 4096;
#pragma unroll
    for (int i = 0; i < 4; ++i) {
      int ci = (w * 4 + i) * 64 + l;
      int row = ci >> 3, cb = ci & 7;
      int sw = (cb ^ (row & 7)) << 3;
      gll(Ksrc + row * 64 + sw, &lds[(w * 4 + i) * 512]);
    }
    // V fragments: direct global->VGPR, issued here so latency hides under
    // the K staging drain + QK MFMAs
    const u16* Vsrc = Vh + jt * 4096 + voff;
    s16x4 av[4][4];
#pragma unroll
    for (int nt = 0; nt < 4; ++nt)
#pragma unroll
      for (int dt = 0; dt < 4; ++dt)
        av[nt][dt] = *(const s16x4*)(Vsrc + (nt * 4 + dt) * 256);
    __syncthreads();  // K staged (drains vmcnt: V regs ready too)
    if (jt * 64 >= rw0 + 32) continue;  // tile fully masked for this wave
    // S^T = K Q^T  (row = n = quad*4+r, col = m = lr)
    f32x4 s[2][4];
#pragma unroll
    for (int mt = 0; mt < 2; ++mt)
#pragma unroll
      for (int nt = 0; nt < 4; ++nt) s[mt][nt] = fz;
#pragma unroll
    for (int cc = 0; cc < 2; ++cc) {
      s16x8 kbf[4];
#pragma unroll
      for (int nt = 0; nt < 4; ++nt)
        kbf[nt] = *(const s16x8*)&lds[(nt * 16 + lr) * 64 + (((cc * 4 + quad) ^ (lr & 7)) << 3)];
#pragma unroll
      for (int mt = 0; mt < 2; ++mt)
#pragma unroll
        for (int nt = 0; nt < 4; ++nt)
          s[mt][nt] = MFMA16(kbf[nt], qf[mt][cc], s[mt][nt]);
    }
    const bool dg = (jt * 64 + 63 > rw0);
    s16x4 pf[2][4];  // P^T fragments, B-operand layout for 16x16x16
#pragma unroll
    for (int mt = 0; mt < 2; ++mt) {
      if (dg) {  // mask BEFORE exp (verified semantics): n_global > m_global
        int T = rw0 + mt * 16 + lr - jt * 64;
#pragma unroll
        for (int nt = 0; nt < 4; ++nt)
#pragma unroll
          for (int r = 0; r < 4; ++r)
            if (nt * 16 + quad * 4 + r > T) s[mt][nt][r] = -1e30f;
      }
      // row max: in-lane over 16 values + 2 cross-quad shuffles (full 64-n max)
      float lm = fmaxf(fmaxf(fmaxf(s[mt][0][0], s[mt][0][1]), fmaxf(s[mt][0][2], s[mt][0][3])),
                       fmaxf(fmaxf(s[mt][1][0], s[mt][1][1]), fmaxf(s[mt][1][2], s[mt][1][3])));
      float lm2 = fmaxf(fmaxf(fmaxf(s[mt][2][0], s[mt][2][1]), fmaxf(s[mt][2][2], s[mt][2][3])),
                        fmaxf(fmaxf(s[mt][3][0], s[mt][3][1]), fmaxf(s[mt][3][2], s[mt][3][3])));
      lm = fmaxf(lm, lm2);
      lm = fmaxf(lm, __shfl_xor(lm, 16));
      lm = fmaxf(lm, __shfl_xor(lm, 32));
      float mn = fmaxf(m_r[mt], lm);
      float al = ex2(m_r[mt] - mn);
      m_r[mt] = mn;
      float ts = 0.f;
#pragma unroll
      for (int nt = 0; nt < 4; ++nt)
#pragma unroll
        for (int r = 0; r < 4; ++r) {
          float p = ex2(s[mt][nt][r] - mn);
          s[mt][nt][r] = p;
          ts += p;
        }
      lp[mt] = lp[mt] * al + ts;
#pragma unroll
      for (int nt = 0; nt < 4; ++nt) {
        s16x4 pk;
        pk[0] = (short)f2bf_fast(s[mt][nt][0]);
        pk[1] = (short)f2bf_fast(s[mt][nt][1]);
        pk[2] = (short)f2bf_fast(s[mt][nt][2]);
        pk[3] = (short)f2bf_fast(s[mt][nt][3]);
        pf[mt][nt] = pk;
      }
#pragma unroll
      for (int dt = 0; dt < 4; ++dt)
#pragma unroll
        for (int r = 0; r < 4; ++r) o[mt][dt][r] *= al;
    }
    // O^T += V^T P^T  (A = V^T frag from regs, B = P^T from regs)
#pragma unroll
    for (int nt = 0; nt < 4; ++nt)
#pragma unroll
      for (int mt = 0; mt < 2; ++mt)
#pragma unroll
        for (int dt = 0; dt < 4; ++dt)
          o[mt][dt] = MFMA1616(av[nt][dt], pf[mt][nt], o[mt][dt]);
  }
  // epilogue: reduce per-lane l across quads, write partials (m, l, unnorm O)
  const int pidx = (bh * 64 + qt) * 4 + c;
#pragma unroll
  for (int mt = 0; mt < 2; ++mt) {
    float lv = lp[mt];
    lv += __shfl_xor(lv, 16);
    lv += __shfl_xor(lv, 32);
    if (quad == 0) {
      pM[pidx * 64 + w * 32 + mt * 16 + lr] = m_r[mt];
      pL[pidx * 64 + w * 32 + mt * 16 + lr] = lv;
    }
#pragma unroll
    for (int dt = 0; dt < 4; ++dt) {
      ushort4 pk;
      pk.x = f2bf(o[mt][dt][0]); pk.y = f2bf(o[mt][dt][1]);
      pk.z = f2bf(o[mt][dt][2]); pk.w = f2bf(o[mt][dt][3]);
      *(ushort4*)&pO[(long)pidx * 4096 + (w * 32 + mt * 16 + lr) * 64 + dt * 16 + quad * 4] = pk;
    }
  }
}

// ---------------- combine partials: exact fp32 log-sum-exp merge ----------------
__global__ __launch_bounds__(128) void k_comb(const u16* __restrict__ pO,
                                              const float* __restrict__ pM,
                                              const float* __restrict__ pL,
                                              u16* __restrict__ Ob) {
  const int bid = blockIdx.x, t = threadIdx.x;
  const int bh = bid >> 6, qt = bid & 63;
  const int nc = (qt + 16) >> 4;  // ceil((qt+1)/16)
  const int row = t >> 1, half = t & 1;
  const int pbase = (bh * 64 + qt) * 4;
  float M = -3.0e38f;
  for (int c = 0; c < nc; ++c) M = fmaxf(M, pM[(pbase + c) * 64 + row]);
  float L = 0.f;
  float acc[32];
#pragma unroll
  for (int d = 0; d < 32; ++d) acc[d] = 0.f;
  for (int c = 0; c < nc; ++c) {
    float wgt = ex2(pM[(pbase + c) * 64 + row] - M);
    L += pL[(pbase + c) * 64 + row] * wgt;
    const u16* src = pO + (long)(pbase + c) * 4096 + row * 64 + half * 32;
#pragma unroll
    for (int k = 0; k < 4; ++k) {
      s16x8 v = *(const s16x8*)(src + k * 8);
#pragma unroll
      for (int j = 0; j < 8; ++j) acc[k * 8 + j] += wgt * bf2f((u16)v[j]);
    }
  }
  float inv = 1.0f / L;
  u16 tmp[32];
#pragma unroll
  for (int d = 0; d < 32; ++d) tmp[d] = f2bf(acc[d] * inv);
  const int b = bh >> 3, h = bh & 7;
  long gbase = (long)(b * 4096 + qt * 64 + row) * 512 + h * 64 + half * 32;
#pragma unroll
  for (int k = 0; k < 4; ++k)
    *(s16x8*)(Ob + gbase + k * 8) = *(const s16x8*)(tmp + k * 8);
}

extern "C" void kernel_launch(void* const* d_in, const int* in_sizes, int n_in,
                              void* d_out, int out_size, void* d_ws, size_t ws_size,
                              hipStream_t stream) {
  const float* x   = (const float*)d_in[0];
  const float* Wq  = (const float*)d_in[1];
  const float* Wkv = (const float*)d_in[2];
  const float* Wo  = (const float*)d_in[3];
  const float* bo  = (const float*)d_in[4];
  float* out = (float*)d_out;
  char* ws = (char*)d_ws;
  const size_t MB = 1048576;
  // ws map: wot 0..0.5M | wqkvt 0.5..2M | Qb 2..10M | Kb 10..18M | Vg 18..26M |
  //         Ob 26..34M | xbf 34..42M | pO 34..66M (overlaps dead xbf) | pM, pL
  u16* wot   = (u16*)(ws);
  u16* wqkvt = (u16*)(ws + MB / 2);
  u16* Qb    = (u16*)(ws + 2 * MB);
  u16* Kb    = (u16*)(ws + 10 * MB);
  u16* Vg    = (u16*)(ws + 18 * MB);
  u16* Ob    = (u16*)(ws + 26 * MB);
  u16* xbf   = (u16*)(ws + 34 * MB);
  u16* pO    = (u16*)(ws + 34 * MB);   // 32 MB: 16*64*4 chunks * 8KB (xbf dead by then)
  float* pM  = (float*)(ws + 66 * MB); // 1 MB
  float* pL  = (float*)(ws + 67 * MB); // 1 MB

  k_prep<<<4352, 256, 0, stream>>>(x, Wq, Wkv, Wo, xbf, wqkvt, wot);
  k_gemm_qkv<<<dim3(64, 12), 256, 0, stream>>>(xbf, wqkvt, Qb, Kb, Vg);
  k_attn_split<<<4096, 128, 0, stream>>>(Qb, Kb, Vg, pO, pM, pL);
  k_comb<<<1024, 128, 0, stream>>>(pO, pM, pL, Ob);
  k_gemm_out<<<dim3(64, 4), 256, 0, stream>>>(Ob, wot, bo, out);
}

// Round 9
// 229.174 us; speedup vs baseline: 1.7059x; 1.7059x over previous
//
#include <hip/hip_runtime.h>

typedef short s16x8 __attribute__((ext_vector_type(8)));
typedef short s16x4 __attribute__((ext_vector_type(4)));
typedef float f32x4 __attribute__((ext_vector_type(4)));
typedef unsigned short u16;
typedef unsigned int u32;

#define MFMA16(a, b, c) __builtin_amdgcn_mfma_f32_16x16x32_bf16((a), (b), (c), 0, 0, 0)
#define MFMA1616(a, b, c) __builtin_amdgcn_mfma_f32_16x16x16bf16_1k((a), (b), (c), 0, 0, 0)

__device__ __forceinline__ u16 f2bf(float f) {
  u32 u = __float_as_uint(f);
  u += 0x7fffu + ((u >> 16) & 1u);
  return (u16)(u >> 16);
}
__device__ __forceinline__ u16 f2bf_fast(float f) {
  return (u16)((__float_as_uint(f) + 0x8000u) >> 16);
}
__device__ __forceinline__ float bf2f(u16 u) {
  return __uint_as_float(((u32)u) << 16);
}
__device__ __forceinline__ float ex2(float x) {
  float r;
  asm("v_exp_f32 %0, %1" : "=v"(r) : "v"(x));
  return r;
}
__device__ __forceinline__ void gll(const u16* g, u16* l) {
  __builtin_amdgcn_global_load_lds((const __attribute__((address_space(1))) u32*)g,
                                   (__attribute__((address_space(3))) u32*)l, 16, 0, 0);
}

// ---------------- fused prep: x->bf16, W^T->bf16 (LDS tile transpose) ----------------
__global__ __launch_bounds__(256) void k_prep(const float* __restrict__ x,
                                              const float* __restrict__ Wq,
                                              const float* __restrict__ Wkv,
                                              const float* __restrict__ Wo,
                                              u16* __restrict__ xb,
                                              u16* __restrict__ wqkvt,
                                              u16* __restrict__ wot) {
  const int bx = blockIdx.x, t = threadIdx.x;
  if (bx < 4096) {
    int i = bx * 256 + t;
    float4 v = ((const float4*)x)[i];
    ushort4 o;
    o.x = f2bf(v.x); o.y = f2bf(v.y); o.z = f2bf(v.z); o.w = f2bf(v.w);
    ((ushort4*)xb)[i] = o;
    return;
  }
  __shared__ u16 tl[64 * 66];
  const float* src; u16* dst; int N, kb, nb;
  if (bx < 4160)      { int tb = bx - 4096; src = Wq;  dst = wqkvt;          N = 512;  kb = tb >> 3; nb = tb & 7; }
  else if (bx < 4288) { int tb = bx - 4160; src = Wkv; dst = wqkvt + 262144; N = 1024; kb = tb >> 4; nb = tb & 15; }
  else                { int tb = bx - 4288; src = Wo;  dst = wot;            N = 512;  kb = tb >> 3; nb = tb & 7; }
#pragma unroll
  for (int it = 0; it < 4; ++it) {
    int idx = it * 256 + t;
    int kl = idx >> 4, nc = idx & 15;
    float4 v = *(const float4*)(src + (kb * 64 + kl) * N + nb * 64 + nc * 4);
    u16* p = &tl[kl * 66 + nc * 4];
    p[0] = f2bf(v.x); p[1] = f2bf(v.y); p[2] = f2bf(v.z); p[3] = f2bf(v.w);
  }
  __syncthreads();
#pragma unroll
  for (int it = 0; it < 2; ++it) {
    int idx = it * 256 + t;
    int nl = idx >> 3, kc = idx & 7;
    u16 tmp[8];
#pragma unroll
    for (int j = 0; j < 8; ++j) tmp[j] = tl[(kc * 8 + j) * 66 + nl];
    *(s16x8*)(dst + (nb * 64 + nl) * 512 + kb * 64 + kc * 8) = *(const s16x8*)tmp;
  }
}

// ---------------- QKV projection GEMM: 128x128 tile, BK=64, async swizzled staging ----------------
// Q/K row-major [bh][n][64]; V in PV-tiled layout [bh][jt][nt][dt][row16=d%16][k16=n%16]
__global__ __launch_bounds__(256, 2) void k_gemm_qkv(
    const u16* __restrict__ A, const u16* __restrict__ Bt,
    u16* __restrict__ Qb, u16* __restrict__ Kb, u16* __restrict__ Vg) {
  __shared__ __align__(16) u16 As[8192], Bs[8192];
  const int t = threadIdx.x, w = t >> 6, l = t & 63, quad = l >> 4, lr = l & 15;
  const int bm = blockIdx.x, bn = blockIdx.y;
  const int wm = (w >> 1) * 64, wn = (w & 1) * 64;
  const f32x4 fz = {0.f, 0.f, 0.f, 0.f};
  f32x4 acc[4][4];
#pragma unroll
  for (int i = 0; i < 4; ++i)
#pragma unroll
    for (int j = 0; j < 4; ++j) acc[i][j] = fz;
  const u16* Ag = A + bm * 128 * 512;
  const u16* Bg = Bt + bn * 128 * 512;
  for (int kk = 0; kk < 8; ++kk) {
    __syncthreads();
#pragma unroll
    for (int i = 0; i < 4; ++i) {
      int ci = w * 256 + i * 64 + l;
      int row = ci >> 3, cb = ci & 7;
      int off = row * 512 + kk * 64 + ((cb ^ (row & 7)) << 3);
      gll(Ag + off, &As[w * 2048 + i * 512]);
      gll(Bg + off, &Bs[w * 2048 + i * 512]);
    }
    __syncthreads();
    s16x8 af[4][2], bf[4][2];
#pragma unroll
    for (int x2 = 0; x2 < 4; ++x2)
#pragma unroll
      for (int c = 0; c < 2; ++c) {
        int sw = ((c * 4 + quad) ^ (lr & 7)) << 3;
        af[x2][c] = *(const s16x8*)&As[(wm + x2 * 16 + lr) * 64 + sw];
        bf[x2][c] = *(const s16x8*)&Bs[(wn + x2 * 16 + lr) * 64 + sw];
      }
#pragma unroll
    for (int c = 0; c < 2; ++c)
#pragma unroll
      for (int ti = 0; ti < 4; ++ti)
#pragma unroll
        for (int tj = 0; tj < 4; ++tj)
          acc[ti][tj] = MFMA16(af[ti][c], bf[tj][c], acc[ti][tj]);
  }
  const int buf = (bn * 128) >> 9;  // uniform: 0=Q,1=K,2=V
  const float QS = 0.0225421107f;   // log2(e)/64
#pragma unroll
  for (int ti = 0; ti < 4; ++ti)
#pragma unroll
    for (int tj = 0; tj < 4; ++tj) {
      int col = bn * 128 + wn + tj * 16 + lr;
      int hd = col & 511, h = hd >> 6, d = hd & 63;
      int row0 = bm * 128 + wm + ti * 16 + quad * 4;
      int b = row0 >> 12, n0 = row0 & 4095;
      long base = (long)(b * 8 + h) * 262144;
      if (buf == 0) {
#pragma unroll
        for (int r = 0; r < 4; ++r) Qb[base + (long)(n0 + r) * 64 + d] = f2bf(acc[ti][tj][r] * QS);
      } else if (buf == 1) {
#pragma unroll
        for (int r = 0; r < 4; ++r) Kb[base + (long)(n0 + r) * 64 + d] = f2bf(acc[ti][tj][r]);
      } else {
        ushort4 pk;
        pk.x = f2bf(acc[ti][tj][0]); pk.y = f2bf(acc[ti][tj][1]);
        pk.z = f2bf(acc[ti][tj][2]); pk.w = f2bf(acc[ti][tj][3]);
        // tiled: offset = ((jt*4+nt)*4+dt)*256 + (d%16)*16 + (n%16); r contiguous in k
        long vaddr = base + ((long)((n0 >> 6) * 4 + ((n0 >> 4) & 3)) * 4 + (d >> 4)) * 256
                     + (long)(d & 15) * 16 + (n0 & 15);
        *(ushort4*)&Vg[vaddr] = pk;
      }
    }
}

// ---------------- output projection GEMM (+bias, fp32 out) ----------------
__global__ __launch_bounds__(256, 2) void k_gemm_out(
    const u16* __restrict__ A, const u16* __restrict__ Bt,
    const float* __restrict__ bias, float* __restrict__ out) {
  __shared__ __align__(16) u16 As[8192], Bs[8192];
  const int t = threadIdx.x, w = t >> 6, l = t & 63, quad = l >> 4, lr = l & 15;
  const int bm = blockIdx.x, bn = blockIdx.y;
  const int wm = (w >> 1) * 64, wn = (w & 1) * 64;
  const f32x4 fz = {0.f, 0.f, 0.f, 0.f};
  f32x4 acc[4][4];
#pragma unroll
  for (int i = 0; i < 4; ++i)
#pragma unroll
    for (int j = 0; j < 4; ++j) acc[i][j] = fz;
  const u16* Ag = A + bm * 128 * 512;
  const u16* Bg = Bt + bn * 128 * 512;
  for (int kk = 0; kk < 8; ++kk) {
    __syncthreads();
#pragma unroll
    for (int i = 0; i < 4; ++i) {
      int ci = w * 256 + i * 64 + l;
      int row = ci >> 3, cb = ci & 7;
      int off = row * 512 + kk * 64 + ((cb ^ (row & 7)) << 3);
      gll(Ag + off, &As[w * 2048 + i * 512]);
      gll(Bg + off, &Bs[w * 2048 + i * 512]);
    }
    __syncthreads();
    s16x8 af[4][2], bf[4][2];
#pragma unroll
    for (int x2 = 0; x2 < 4; ++x2)
#pragma unroll
      for (int c = 0; c < 2; ++c) {
        int sw = ((c * 4 + quad) ^ (lr & 7)) << 3;
        af[x2][c] = *(const s16x8*)&As[(wm + x2 * 16 + lr) * 64 + sw];
        bf[x2][c] = *(const s16x8*)&Bs[(wn + x2 * 16 + lr) * 64 + sw];
      }
#pragma unroll
    for (int c = 0; c < 2; ++c)
#pragma unroll
      for (int ti = 0; ti < 4; ++ti)
#pragma unroll
        for (int tj = 0; tj < 4; ++tj)
          acc[ti][tj] = MFMA16(af[ti][c], bf[tj][c], acc[ti][tj]);
  }
#pragma unroll
  for (int ti = 0; ti < 4; ++ti)
#pragma unroll
    for (int tj = 0; tj < 4; ++tj) {
      int col = bn * 128 + wn + tj * 16 + lr;
      float bb = bias[col];
#pragma unroll
      for (int r = 0; r < 4; ++r) {
        int row = bm * 128 + wm + ti * 16 + quad * 4 + r;
        out[(long)row * 512 + col] = acc[ti][tj][r] + bb;
      }
    }
}

// ---------------- K-split flash attention, S^T engine, register-direct V ----------------
// grid 4096 = (64 qt desc) x (16 bh) x (4 c); 128 thr = 2 waves x 32 q-rows.
// S^T = K·Q^T; softmax row m = lane&15 (in-lane max + 2 shuffles); P^T stays in
// registers (B-operand of 16x16x16). V fragments load straight global->VGPR.
// LDS 8KB = K only.
// NOTE: launch_bounds min-waves MUST stay <=2: at 4 the allocator caps VGPR at 64
// and spills ~480MB/launch to scratch (R8 regression: WRITE_SIZE 292MB, 295us).
__global__ __launch_bounds__(128, 2) void k_attn_split(
    const u16* __restrict__ Qb, const u16* __restrict__ Kb,
    const u16* __restrict__ Vg, u16* __restrict__ pO,
    float* __restrict__ pM, float* __restrict__ pL) {
  const int bid = blockIdx.x;
  const int qt = 63 - (bid >> 6), rem = bid & 63, bh = rem >> 2, c = rem & 3;
  const int jcount = qt + 1;
  const int nc = (jcount + 15) >> 4;
  if (c >= nc) return;  // block-uniform early exit (before any barrier)
  const int jstart = c * 16;
  const int jendx = (jstart + 16 < jcount) ? jstart + 16 : jcount;
  __shared__ __align__(16) u16 lds[4096];  // K tile only
  const int t = threadIdx.x, w = t >> 6, l = t & 63, quad = l >> 4, lr = l & 15;
  const u16* Qh = Qb + (long)bh * 262144;
  const u16* Kh = Kb + (long)bh * 262144;
  const u16* Vh = Vg + (long)bh * 262144;
  const int rw0 = qt * 64 + w * 32;
  s16x8 qf[2][2];
#pragma unroll
  for (int mt = 0; mt < 2; ++mt)
#pragma unroll
    for (int cc = 0; cc < 2; ++cc)
      qf[mt][cc] = *(const s16x8*)(Qh + (rw0 + mt * 16 + lr) * 64 + cc * 32 + quad * 8);
  const f32x4 fz = {0.f, 0.f, 0.f, 0.f};
  f32x4 o[2][4];  // O^T: [mt][dt], C-layout col=m=lr, row=d=quad*4+r
#pragma unroll
  for (int mt = 0; mt < 2; ++mt)
#pragma unroll
    for (int dt = 0; dt < 4; ++dt) o[mt][dt] = fz;
  float m_r[2] = {-3.0e38f, -3.0e38f};
  float lp[2] = {0.f, 0.f};  // per-lane l partials (quad-subset of n)
  const int voff = lr * 16 + quad * 4;  // per-lane V fragment offset within 256-elem tile

  for (int jt = jstart; jt < jendx; ++jt) {
    __syncthreads();  // all waves done reading previous K tile
    const u16* Ksrc = Kh + jt * 4096;
#pragma unroll
    for (int i = 0; i < 4; ++i) {
      int ci = (w * 4 + i) * 64 + l;
      int row = ci >> 3, cb = ci & 7;
      int sw = (cb ^ (row & 7)) << 3;
      gll(Ksrc + row * 64 + sw, &lds[(w * 4 + i) * 512]);
    }
    // V fragments: direct global->VGPR, issued here so latency hides under
    // the K staging drain + QK MFMAs
    const u16* Vsrc = Vh + jt * 4096 + voff;
    s16x4 av[4][4];
#pragma unroll
    for (int nt = 0; nt < 4; ++nt)
#pragma unroll
      for (int dt = 0; dt < 4; ++dt)
        av[nt][dt] = *(const s16x4*)(Vsrc + (nt * 4 + dt) * 256);
    __syncthreads();  // K staged (drains vmcnt: V regs ready too)
    if (jt * 64 >= rw0 + 32) continue;  // tile fully masked for this wave
    // S^T = K Q^T  (row = n = quad*4+r, col = m = lr)
    f32x4 s[2][4];
#pragma unroll
    for (int mt = 0; mt < 2; ++mt)
#pragma unroll
      for (int nt = 0; nt < 4; ++nt) s[mt][nt] = fz;
#pragma unroll
    for (int cc = 0; cc < 2; ++cc) {
      s16x8 kbf[4];
#pragma unroll
      for (int nt = 0; nt < 4; ++nt)
        kbf[nt] = *(const s16x8*)&lds[(nt * 16 + lr) * 64 + (((cc * 4 + quad) ^ (lr & 7)) << 3)];
#pragma unroll
      for (int mt = 0; mt < 2; ++mt)
#pragma unroll
        for (int nt = 0; nt < 4; ++nt)
          s[mt][nt] = MFMA16(kbf[nt], qf[mt][cc], s[mt][nt]);
    }
    const bool dg = (jt * 64 + 63 > rw0);
    s16x4 pf[2][4];  // P^T fragments, B-operand layout for 16x16x16
#pragma unroll
    for (int mt = 0; mt < 2; ++mt) {
      if (dg) {  // mask BEFORE exp (verified semantics): n_global > m_global
        int T = rw0 + mt * 16 + lr - jt * 64;
#pragma unroll
        for (int nt = 0; nt < 4; ++nt)
#pragma unroll
          for (int r = 0; r < 4; ++r)
            if (nt * 16 + quad * 4 + r > T) s[mt][nt][r] = -1e30f;
      }
      // row max: in-lane over 16 values + 2 cross-quad shuffles (full 64-n max)
      float lm = fmaxf(fmaxf(fmaxf(s[mt][0][0], s[mt][0][1]), fmaxf(s[mt][0][2], s[mt][0][3])),
                       fmaxf(fmaxf(s[mt][1][0], s[mt][1][1]), fmaxf(s[mt][1][2], s[mt][1][3])));
      float lm2 = fmaxf(fmaxf(fmaxf(s[mt][2][0], s[mt][2][1]), fmaxf(s[mt][2][2], s[mt][2][3])),
                        fmaxf(fmaxf(s[mt][3][0], s[mt][3][1]), fmaxf(s[mt][3][2], s[mt][3][3])));
      lm = fmaxf(lm, lm2);
      lm = fmaxf(lm, __shfl_xor(lm, 16));
      lm = fmaxf(lm, __shfl_xor(lm, 32));
      float mn = fmaxf(m_r[mt], lm);
      float al = ex2(m_r[mt] - mn);
      m_r[mt] = mn;
      float ts = 0.f;
#pragma unroll
      for (int nt = 0; nt < 4; ++nt)
#pragma unroll
        for (int r = 0; r < 4; ++r) {
          float p = ex2(s[mt][nt][r] - mn);
          s[mt][nt][r] = p;
          ts += p;
        }
      lp[mt] = lp[mt] * al + ts;
#pragma unroll
      for (int nt = 0; nt < 4; ++nt) {
        s16x4 pk;
        pk[0] = (short)f2bf_fast(s[mt][nt][0]);
        pk[1] = (short)f2bf_fast(s[mt][nt][1]);
        pk[2] = (short)f2bf_fast(s[mt][nt][2]);
        pk[3] = (short)f2bf_fast(s[mt][nt][3]);
        pf[mt][nt] = pk;
      }
#pragma unroll
      for (int dt = 0; dt < 4; ++dt)
#pragma unroll
        for (int r = 0; r < 4; ++r) o[mt][dt][r] *= al;
    }
    // O^T += V^T P^T  (A = V^T frag from regs, B = P^T from regs)
#pragma unroll
    for (int nt = 0; nt < 4; ++nt)
#pragma unroll
      for (int mt = 0; mt < 2; ++mt)
#pragma unroll
        for (int dt = 0; dt < 4; ++dt)
          o[mt][dt] = MFMA1616(av[nt][dt], pf[mt][nt], o[mt][dt]);
  }
  // epilogue: reduce per-lane l across quads, write partials (m, l, unnorm O)
  const int pidx = (bh * 64 + qt) * 4 + c;
#pragma unroll
  for (int mt = 0; mt < 2; ++mt) {
    float lv = lp[mt];
    lv += __shfl_xor(lv, 16);
    lv += __shfl_xor(lv, 32);
    if (quad == 0) {
      pM[pidx * 64 + w * 32 + mt * 16 + lr] = m_r[mt];
      pL[pidx * 64 + w * 32 + mt * 16 + lr] = lv;
    }
#pragma unroll
    for (int dt = 0; dt < 4; ++dt) {
      ushort4 pk;
      pk.x = f2bf(o[mt][dt][0]); pk.y = f2bf(o[mt][dt][1]);
      pk.z = f2bf(o[mt][dt][2]); pk.w = f2bf(o[mt][dt][3]);
      *(ushort4*)&pO[(long)pidx * 4096 + (w * 32 + mt * 16 + lr) * 64 + dt * 16 + quad * 4] = pk;
    }
  }
}

// ---------------- combine partials: exact fp32 log-sum-exp merge ----------------
__global__ __launch_bounds__(128) void k_comb(const u16* __restrict__ pO,
                                              const float* __restrict__ pM,
                                              const float* __restrict__ pL,
                                              u16* __restrict__ Ob) {
  const int bid = blockIdx.x, t = threadIdx.x;
  const int bh = bid >> 6, qt = bid & 63;
  const int nc = (qt + 16) >> 4;  // ceil((qt+1)/16)
  const int row = t >> 1, half = t & 1;
  const int pbase = (bh * 64 + qt) * 4;
  float M = -3.0e38f;
  for (int c = 0; c < nc; ++c) M = fmaxf(M, pM[(pbase + c) * 64 + row]);
  float L = 0.f;
  float acc[32];
#pragma unroll
  for (int d = 0; d < 32; ++d) acc[d] = 0.f;
  for (int c = 0; c < nc; ++c) {
    float wgt = ex2(pM[(pbase + c) * 64 + row] - M);
    L += pL[(pbase + c) * 64 + row] * wgt;
    const u16* src = pO + (long)(pbase + c) * 4096 + row * 64 + half * 32;
#pragma unroll
    for (int k = 0; k < 4; ++k) {
      s16x8 v = *(const s16x8*)(src + k * 8);
#pragma unroll
      for (int j = 0; j < 8; ++j) acc[k * 8 + j] += wgt * bf2f((u16)v[j]);
    }
  }
  float inv = 1.0f / L;
  u16 tmp[32];
#pragma unroll
  for (int d = 0; d < 32; ++d) tmp[d] = f2bf(acc[d] * inv);
  const int b = bh >> 3, h = bh & 7;
  long gbase = (long)(b * 4096 + qt * 64 + row) * 512 + h * 64 + half * 32;
#pragma unroll
  for (int k = 0; k < 4; ++k)
    *(s16x8*)(Ob + gbase + k * 8) = *(const s16x8*)(tmp + k * 8);
}

extern "C" void kernel_launch(void* const* d_in, const int* in_sizes, int n_in,
                              void* d_out, int out_size, void* d_ws, size_t ws_size,
                              hipStream_t stream) {
  const float* x   = (const float*)d_in[0];
  const float* Wq  = (const float*)d_in[1];
  const float* Wkv = (const float*)d_in[2];
  const float* Wo  = (const float*)d_in[3];
  const float* bo  = (const float*)d_in[4];
  float* out = (float*)d_out;
  char* ws = (char*)d_ws;
  const size_t MB = 1048576;
  // ws map: wot 0..0.5M | wqkvt 0.5..2M | Qb 2..10M | Kb 10..18M | Vg 18..26M |
  //         Ob 26..34M | xbf 34..42M | pO 34..66M (overlaps dead xbf) | pM, pL
  u16* wot   = (u16*)(ws);
  u16* wqkvt = (u16*)(ws + MB / 2);
  u16* Qb    = (u16*)(ws + 2 * MB);
  u16* Kb    = (u16*)(ws + 10 * MB);
  u16* Vg    = (u16*)(ws + 18 * MB);
  u16* Ob    = (u16*)(ws + 26 * MB);
  u16* xbf   = (u16*)(ws + 34 * MB);
  u16* pO    = (u16*)(ws + 34 * MB);   // 32 MB: 16*64*4 chunks * 8KB (xbf dead by then)
  float* pM  = (float*)(ws + 66 * MB); // 1 MB
  float* pL  = (float*)(ws + 67 * MB); // 1 MB

  k_prep<<<4352, 256, 0, stream>>>(x, Wq, Wkv, Wo, xbf, wqkvt, wot);
  k_gemm_qkv<<<dim3(64, 12), 256, 0, stream>>>(xbf, wqkvt, Qb, Kb, Vg);
  k_attn_split<<<4096, 128, 0, stream>>>(Qb, Kb, Vg, pO, pM, pL);
  k_comb<<<1024, 128, 0, stream>>>(pO, pM, pL, Ob);
  k_gemm_out<<<dim3(64, 4), 256, 0, stream>>>(Ob, wot, bo, out);
}

// Round 10
// 216.006 us; speedup vs baseline: 1.8099x; 1.0610x over previous
//
#include <hip/hip_runtime.h>

typedef short s16x8 __attribute__((ext_vector_type(8)));
typedef short s16x4 __attribute__((ext_vector_type(4)));
typedef float f32x4 __attribute__((ext_vector_type(4)));
typedef unsigned short u16;
typedef unsigned int u32;

#define MFMA16(a, b, c) __builtin_amdgcn_mfma_f32_16x16x32_bf16((a), (b), (c), 0, 0, 0)
#define MFMA1616(a, b, c) __builtin_amdgcn_mfma_f32_16x16x16bf16_1k((a), (b), (c), 0, 0, 0)

__device__ __forceinline__ u16 f2bf(float f) {
  u32 u = __float_as_uint(f);
  u += 0x7fffu + ((u >> 16) & 1u);
  return (u16)(u >> 16);
}
__device__ __forceinline__ u16 f2bf_fast(float f) {
  return (u16)((__float_as_uint(f) + 0x8000u) >> 16);
}
__device__ __forceinline__ float bf2f(u16 u) {
  return __uint_as_float(((u32)u) << 16);
}
__device__ __forceinline__ float ex2(float x) {
  float r;
  asm("v_exp_f32 %0, %1" : "=v"(r) : "v"(x));
  return r;
}
__device__ __forceinline__ void gll(const u16* g, u16* l) {
  __builtin_amdgcn_global_load_lds((const __attribute__((address_space(1))) u32*)g,
                                   (__attribute__((address_space(3))) u32*)l, 16, 0, 0);
}

// ---------------- fused prep: x->bf16, W^T->bf16 (LDS tile transpose) ----------------
__global__ __launch_bounds__(256) void k_prep(const float* __restrict__ x,
                                              const float* __restrict__ Wq,
                                              const float* __restrict__ Wkv,
                                              const float* __restrict__ Wo,
                                              u16* __restrict__ xb,
                                              u16* __restrict__ wqkvt,
                                              u16* __restrict__ wot) {
  const int bx = blockIdx.x, t = threadIdx.x;
  if (bx < 4096) {
    int i = bx * 256 + t;
    float4 v = ((const float4*)x)[i];
    ushort4 o;
    o.x = f2bf(v.x); o.y = f2bf(v.y); o.z = f2bf(v.z); o.w = f2bf(v.w);
    ((ushort4*)xb)[i] = o;
    return;
  }
  __shared__ u16 tl[64 * 66];
  const float* src; u16* dst; int N, kb, nb;
  if (bx < 4160)      { int tb = bx - 4096; src = Wq;  dst = wqkvt;          N = 512;  kb = tb >> 3; nb = tb & 7; }
  else if (bx < 4288) { int tb = bx - 4160; src = Wkv; dst = wqkvt + 262144; N = 1024; kb = tb >> 4; nb = tb & 15; }
  else                { int tb = bx - 4288; src = Wo;  dst = wot;            N = 512;  kb = tb >> 3; nb = tb & 7; }
#pragma unroll
  for (int it = 0; it < 4; ++it) {
    int idx = it * 256 + t;
    int kl = idx >> 4, nc = idx & 15;
    float4 v = *(const float4*)(src + (kb * 64 + kl) * N + nb * 64 + nc * 4);
    u16* p = &tl[kl * 66 + nc * 4];
    p[0] = f2bf(v.x); p[1] = f2bf(v.y); p[2] = f2bf(v.z); p[3] = f2bf(v.w);
  }
  __syncthreads();
#pragma unroll
  for (int it = 0; it < 2; ++it) {
    int idx = it * 256 + t;
    int nl = idx >> 3, kc = idx & 7;
    u16 tmp[8];
#pragma unroll
    for (int j = 0; j < 8; ++j) tmp[j] = tl[(kc * 8 + j) * 66 + nl];
    *(s16x8*)(dst + (nb * 64 + nl) * 512 + kb * 64 + kc * 8) = *(const s16x8*)tmp;
  }
}

// ---------------- QKV projection GEMM: 128x128 tile, BK=64, async swizzled staging ----------------
// Q/K row-major [bh][n][64]; V in PV-tiled layout [bh][jt][nt][dt][row16=d%16][k16=n%16]
__global__ __launch_bounds__(256, 2) void k_gemm_qkv(
    const u16* __restrict__ A, const u16* __restrict__ Bt,
    u16* __restrict__ Qb, u16* __restrict__ Kb, u16* __restrict__ Vg) {
  __shared__ __align__(16) u16 As[8192], Bs[8192];
  const int t = threadIdx.x, w = t >> 6, l = t & 63, quad = l >> 4, lr = l & 15;
  const int bm = blockIdx.x, bn = blockIdx.y;
  const int wm = (w >> 1) * 64, wn = (w & 1) * 64;
  const f32x4 fz = {0.f, 0.f, 0.f, 0.f};
  f32x4 acc[4][4];
#pragma unroll
  for (int i = 0; i < 4; ++i)
#pragma unroll
    for (int j = 0; j < 4; ++j) acc[i][j] = fz;
  const u16* Ag = A + bm * 128 * 512;
  const u16* Bg = Bt + bn * 128 * 512;
  for (int kk = 0; kk < 8; ++kk) {
    __syncthreads();
#pragma unroll
    for (int i = 0; i < 4; ++i) {
      int ci = w * 256 + i * 64 + l;
      int row = ci >> 3, cb = ci & 7;
      int off = row * 512 + kk * 64 + ((cb ^ (row & 7)) << 3);
      gll(Ag + off, &As[w * 2048 + i * 512]);
      gll(Bg + off, &Bs[w * 2048 + i * 512]);
    }
    __syncthreads();
    s16x8 af[4][2], bf[4][2];
#pragma unroll
    for (int x2 = 0; x2 < 4; ++x2)
#pragma unroll
      for (int c = 0; c < 2; ++c) {
        int sw = ((c * 4 + quad) ^ (lr & 7)) << 3;
        af[x2][c] = *(const s16x8*)&As[(wm + x2 * 16 + lr) * 64 + sw];
        bf[x2][c] = *(const s16x8*)&Bs[(wn + x2 * 16 + lr) * 64 + sw];
      }
#pragma unroll
    for (int c = 0; c < 2; ++c)
#pragma unroll
      for (int ti = 0; ti < 4; ++ti)
#pragma unroll
        for (int tj = 0; tj < 4; ++tj)
          acc[ti][tj] = MFMA16(af[ti][c], bf[tj][c], acc[ti][tj]);
  }
  const int buf = (bn * 128) >> 9;  // uniform: 0=Q,1=K,2=V
  const float QS = 0.0225421107f;   // log2(e)/64
#pragma unroll
  for (int ti = 0; ti < 4; ++ti)
#pragma unroll
    for (int tj = 0; tj < 4; ++tj) {
      int col = bn * 128 + wn + tj * 16 + lr;
      int hd = col & 511, h = hd >> 6, d = hd & 63;
      int row0 = bm * 128 + wm + ti * 16 + quad * 4;
      int b = row0 >> 12, n0 = row0 & 4095;
      long base = (long)(b * 8 + h) * 262144;
      if (buf == 0) {
#pragma unroll
        for (int r = 0; r < 4; ++r) Qb[base + (long)(n0 + r) * 64 + d] = f2bf(acc[ti][tj][r] * QS);
      } else if (buf == 1) {
#pragma unroll
        for (int r = 0; r < 4; ++r) Kb[base + (long)(n0 + r) * 64 + d] = f2bf(acc[ti][tj][r]);
      } else {
        ushort4 pk;
        pk.x = f2bf(acc[ti][tj][0]); pk.y = f2bf(acc[ti][tj][1]);
        pk.z = f2bf(acc[ti][tj][2]); pk.w = f2bf(acc[ti][tj][3]);
        // tiled: offset = ((jt*4+nt)*4+dt)*256 + (d%16)*16 + (n%16); r contiguous in k
        long vaddr = base + ((long)((n0 >> 6) * 4 + ((n0 >> 4) & 3)) * 4 + (d >> 4)) * 256
                     + (long)(d & 15) * 16 + (n0 & 15);
        *(ushort4*)&Vg[vaddr] = pk;
      }
    }
}

// ---------------- output projection GEMM (+bias, fp32 out) ----------------
__global__ __launch_bounds__(256, 2) void k_gemm_out(
    const u16* __restrict__ A, const u16* __restrict__ Bt,
    const float* __restrict__ bias, float* __restrict__ out) {
  __shared__ __align__(16) u16 As[8192], Bs[8192];
  const int t = threadIdx.x, w = t >> 6, l = t & 63, quad = l >> 4, lr = l & 15;
  const int bm = blockIdx.x, bn = blockIdx.y;
  const int wm = (w >> 1) * 64, wn = (w & 1) * 64;
  const f32x4 fz = {0.f, 0.f, 0.f, 0.f};
  f32x4 acc[4][4];
#pragma unroll
  for (int i = 0; i < 4; ++i)
#pragma unroll
    for (int j = 0; j < 4; ++j) acc[i][j] = fz;
  const u16* Ag = A + bm * 128 * 512;
  const u16* Bg = Bt + bn * 128 * 512;
  for (int kk = 0; kk < 8; ++kk) {
    __syncthreads();
#pragma unroll
    for (int i = 0; i < 4; ++i) {
      int ci = w * 256 + i * 64 + l;
      int row = ci >> 3, cb = ci & 7;
      int off = row * 512 + kk * 64 + ((cb ^ (row & 7)) << 3);
      gll(Ag + off, &As[w * 2048 + i * 512]);
      gll(Bg + off, &Bs[w * 2048 + i * 512]);
    }
    __syncthreads();
    s16x8 af[4][2], bf[4][2];
#pragma unroll
    for (int x2 = 0; x2 < 4; ++x2)
#pragma unroll
      for (int c = 0; c < 2; ++c) {
        int sw = ((c * 4 + quad) ^ (lr & 7)) << 3;
        af[x2][c] = *(const s16x8*)&As[(wm + x2 * 16 + lr) * 64 + sw];
        bf[x2][c] = *(const s16x8*)&Bs[(wn + x2 * 16 + lr) * 64 + sw];
      }
#pragma unroll
    for (int c = 0; c < 2; ++c)
#pragma unroll
      for (int ti = 0; ti < 4; ++ti)
#pragma unroll
        for (int tj = 0; tj < 4; ++tj)
          acc[ti][tj] = MFMA16(af[ti][c], bf[tj][c], acc[ti][tj]);
  }
#pragma unroll
  for (int ti = 0; ti < 4; ++ti)
#pragma unroll
    for (int tj = 0; tj < 4; ++tj) {
      int col = bn * 128 + wn + tj * 16 + lr;
      float bb = bias[col];
#pragma unroll
      for (int r = 0; r < 4; ++r) {
        int row = bm * 128 + wm + ti * 16 + quad * 4 + r;
        out[(long)row * 512 + col] = acc[ti][tj][r] + bb;
      }
    }
}

// ---- helpers for the pipelined attention loop (forceinline: compile-time av set) ----
__device__ __forceinline__ void stage_tile(const u16* Kh, const u16* Vh, int jt,
                                           u16* ldsbuf, s16x4 (&av)[4][4],
                                           int w, int l, int voff) {
  const u16* Ksrc = Kh + jt * 4096;
#pragma unroll
  for (int i = 0; i < 4; ++i) {
    int ci = (w * 4 + i) * 64 + l;
    int row = ci >> 3, cb = ci & 7;
    int sw = (cb ^ (row & 7)) << 3;
    gll(Ksrc + row * 64 + sw, ldsbuf + (w * 4 + i) * 512);
  }
  const u16* Vsrc = Vh + jt * 4096 + voff;
#pragma unroll
  for (int nt = 0; nt < 4; ++nt)
#pragma unroll
    for (int dt = 0; dt < 4; ++dt)
      av[nt][dt] = *(const s16x4*)(Vsrc + (nt * 4 + dt) * 256);
}

__device__ __forceinline__ void attn_tile(const u16* Ks, const s16x4 (&av)[4][4],
                                          const s16x8 (&qf)[2][2], f32x4 (&o)[2][4],
                                          float (&m_r)[2], float (&lp)[2],
                                          int jt, int rw0, int quad, int lr) {
  const f32x4 fz = {0.f, 0.f, 0.f, 0.f};
  // S^T = K Q^T  (row = n = quad*4+r, col = m = lr)
  f32x4 s[2][4];
#pragma unroll
  for (int mt = 0; mt < 2; ++mt)
#pragma unroll
    for (int nt = 0; nt < 4; ++nt) s[mt][nt] = fz;
#pragma unroll
  for (int cc = 0; cc < 2; ++cc) {
    s16x8 kbf[4];
#pragma unroll
    for (int nt = 0; nt < 4; ++nt)
      kbf[nt] = *(const s16x8*)&Ks[(nt * 16 + lr) * 64 + (((cc * 4 + quad) ^ (lr & 7)) << 3)];
#pragma unroll
    for (int mt = 0; mt < 2; ++mt)
#pragma unroll
      for (int nt = 0; nt < 4; ++nt)
        s[mt][nt] = MFMA16(kbf[nt], qf[mt][cc], s[mt][nt]);
  }
  const bool dg = (jt * 64 + 63 > rw0);
  s16x4 pf[2][4];  // P^T fragments, B-operand layout for 16x16x16
#pragma unroll
  for (int mt = 0; mt < 2; ++mt) {
    if (dg) {  // mask BEFORE exp (verified semantics): n_global > m_global
      int T = rw0 + mt * 16 + lr - jt * 64;
#pragma unroll
      for (int nt = 0; nt < 4; ++nt)
#pragma unroll
        for (int r = 0; r < 4; ++r)
          if (nt * 16 + quad * 4 + r > T) s[mt][nt][r] = -1e30f;
    }
    // row max: in-lane over 16 values + 2 cross-quad shuffles (full 64-n max)
    float lm = fmaxf(fmaxf(fmaxf(s[mt][0][0], s[mt][0][1]), fmaxf(s[mt][0][2], s[mt][0][3])),
                     fmaxf(fmaxf(s[mt][1][0], s[mt][1][1]), fmaxf(s[mt][1][2], s[mt][1][3])));
    float lm2 = fmaxf(fmaxf(fmaxf(s[mt][2][0], s[mt][2][1]), fmaxf(s[mt][2][2], s[mt][2][3])),
                      fmaxf(fmaxf(s[mt][3][0], s[mt][3][1]), fmaxf(s[mt][3][2], s[mt][3][3])));
    lm = fmaxf(lm, lm2);
    lm = fmaxf(lm, __shfl_xor(lm, 16));
    lm = fmaxf(lm, __shfl_xor(lm, 32));
    float mn = fmaxf(m_r[mt], lm);
    float al = ex2(m_r[mt] - mn);
    m_r[mt] = mn;
    float ts = 0.f;
#pragma unroll
    for (int nt = 0; nt < 4; ++nt)
#pragma unroll
      for (int r = 0; r < 4; ++r) {
        float p = ex2(s[mt][nt][r] - mn);
        s[mt][nt][r] = p;
        ts += p;
      }
    lp[mt] = lp[mt] * al + ts;
#pragma unroll
    for (int nt = 0; nt < 4; ++nt) {
      s16x4 pk;
      pk[0] = (short)f2bf_fast(s[mt][nt][0]);
      pk[1] = (short)f2bf_fast(s[mt][nt][1]);
      pk[2] = (short)f2bf_fast(s[mt][nt][2]);
      pk[3] = (short)f2bf_fast(s[mt][nt][3]);
      pf[mt][nt] = pk;
    }
#pragma unroll
    for (int dt = 0; dt < 4; ++dt)
#pragma unroll
      for (int r = 0; r < 4; ++r) o[mt][dt][r] *= al;
  }
  // O^T += V^T P^T  (A = V^T frag from regs, B = P^T from regs)
#pragma unroll
  for (int nt = 0; nt < 4; ++nt)
#pragma unroll
    for (int mt = 0; mt < 2; ++mt)
#pragma unroll
      for (int dt = 0; dt < 4; ++dt)
        o[mt][dt] = MFMA1616(av[nt][dt], pf[mt][nt], o[mt][dt]);
}

// ---------------- K-split flash attention: pipelined S^T engine ----------------
// grid 4096 = (64 qt desc) x (16 bh) x (4 c); 128 thr = 2 waves x 32 q-rows.
// Double-buffered K (LDS 2x4KB) + double-buffered V (register sets av0/av1,
// compile-time distinct — runtime indexing would spill). Loop: issue jt+1's
// K-gll + V-loads FIRST, compute jt, then one barrier — so the vmcnt(0) drain
// at the barrier lands after ~600cy of compute, hiding the load latency.
// NOTE: launch_bounds min-waves MUST stay <=2 (R8: 4 -> 64-VGPR cap -> 480MB spill).
__global__ __launch_bounds__(128, 2) void k_attn_split(
    const u16* __restrict__ Qb, const u16* __restrict__ Kb,
    const u16* __restrict__ Vg, u16* __restrict__ pO,
    float* __restrict__ pM, float* __restrict__ pL) {
  const int bid = blockIdx.x;
  const int qt = 63 - (bid >> 6), rem = bid & 63, bh = rem >> 2, c = rem & 3;
  const int jcount = qt + 1;
  const int nc = (jcount + 15) >> 4;
  if (c >= nc) return;  // block-uniform early exit (before any barrier)
  const int jstart = c * 16;
  const int jendx = (jstart + 16 < jcount) ? jstart + 16 : jcount;
  __shared__ __align__(16) u16 lds[8192];  // K double buffer
  const int t = threadIdx.x, w = t >> 6, l = t & 63, quad = l >> 4, lr = l & 15;
  const u16* Qh = Qb + (long)bh * 262144;
  const u16* Kh = Kb + (long)bh * 262144;
  const u16* Vh = Vg + (long)bh * 262144;
  const int rw0 = qt * 64 + w * 32;
  const int voff = lr * 16 + quad * 4;
  s16x4 av0[4][4], av1[4][4];
  // prologue: stage first tile into buf0/av0 (issue before Q loads so it flies)
  stage_tile(Kh, Vh, jstart, &lds[0], av0, w, l, voff);
  s16x8 qf[2][2];
#pragma unroll
  for (int mt = 0; mt < 2; ++mt)
#pragma unroll
    for (int cc = 0; cc < 2; ++cc)
      qf[mt][cc] = *(const s16x8*)(Qh + (rw0 + mt * 16 + lr) * 64 + cc * 32 + quad * 8);
  const f32x4 fz = {0.f, 0.f, 0.f, 0.f};
  f32x4 o[2][4];  // O^T: [mt][dt], C-layout col=m=lr, row=d=quad*4+r
#pragma unroll
  for (int mt = 0; mt < 2; ++mt)
#pragma unroll
    for (int dt = 0; dt < 4; ++dt) o[mt][dt] = fz;
  float m_r[2] = {-3.0e38f, -3.0e38f};
  float lp[2] = {0.f, 0.f};
  __syncthreads();  // first tile staged

  int jt = jstart;
  while (true) {
    // even step: compute buf0/av0, prefetch jt+1 -> buf1/av1
    if (jt + 1 < jendx) stage_tile(Kh, Vh, jt + 1, &lds[4096], av1, w, l, voff);
    attn_tile(&lds[0], av0, qf, o, m_r, lp, jt, rw0, quad, lr);
    __syncthreads();  // drains jt+1 loads (after compute) + buffer safety
    ++jt;
    if (jt >= jendx) break;
    // odd step: compute buf1/av1, prefetch jt+1 -> buf0/av0
    if (jt + 1 < jendx) stage_tile(Kh, Vh, jt + 1, &lds[0], av0, w, l, voff);
    attn_tile(&lds[4096], av1, qf, o, m_r, lp, jt, rw0, quad, lr);
    __syncthreads();
    ++jt;
    if (jt >= jendx) break;
  }
  // epilogue: reduce per-lane l across quads, write partials (m, l, unnorm O)
  const int pidx = (bh * 64 + qt) * 4 + c;
#pragma unroll
  for (int mt = 0; mt < 2; ++mt) {
    float lv = lp[mt];
    lv += __shfl_xor(lv, 16);
    lv += __shfl_xor(lv, 32);
    if (quad == 0) {
      pM[pidx * 64 + w * 32 + mt * 16 + lr] = m_r[mt];
      pL[pidx * 64 + w * 32 + mt * 16 + lr] = lv;
    }
#pragma unroll
    for (int dt = 0; dt < 4; ++dt) {
      ushort4 pk;
      pk.x = f2bf(o[mt][dt][0]); pk.y = f2bf(o[mt][dt][1]);
      pk.z = f2bf(o[mt][dt][2]); pk.w = f2bf(o[mt][dt][3]);
      *(ushort4*)&pO[(long)pidx * 4096 + (w * 32 + mt * 16 + lr) * 64 + dt * 16 + quad * 4] = pk;
    }
  }
}

// ---------------- combine partials: exact fp32 log-sum-exp merge ----------------
__global__ __launch_bounds__(128) void k_comb(const u16* __restrict__ pO,
                                              const float* __restrict__ pM,
                                              const float* __restrict__ pL,
                                              u16* __restrict__ Ob) {
  const int bid = blockIdx.x, t = threadIdx.x;
  const int bh = bid >> 6, qt = bid & 63;
  const int nc = (qt + 16) >> 4;  // ceil((qt+1)/16)
  const int row = t >> 1, half = t & 1;
  const int pbase = (bh * 64 + qt) * 4;
  float M = -3.0e38f;
  for (int c = 0; c < nc; ++c) M = fmaxf(M, pM[(pbase + c) * 64 + row]);
  float L = 0.f;
  float acc[32];
#pragma unroll
  for (int d = 0; d < 32; ++d) acc[d] = 0.f;
  for (int c = 0; c < nc; ++c) {
    float wgt = ex2(pM[(pbase + c) * 64 + row] - M);
    L += pL[(pbase + c) * 64 + row] * wgt;
    const u16* src = pO + (long)(pbase + c) * 4096 + row * 64 + half * 32;
#pragma unroll
    for (int k = 0; k < 4; ++k) {
      s16x8 v = *(const s16x8*)(src + k * 8);
#pragma unroll
      for (int j = 0; j < 8; ++j) acc[k * 8 + j] += wgt * bf2f((u16)v[j]);
    }
  }
  float inv = 1.0f / L;
  u16 tmp[32];
#pragma unroll
  for (int d = 0; d < 32; ++d) tmp[d] = f2bf(acc[d] * inv);
  const int b = bh >> 3, h = bh & 7;
  long gbase = (long)(b * 4096 + qt * 64 + row) * 512 + h * 64 + half * 32;
#pragma unroll
  for (int k = 0; k < 4; ++k)
    *(s16x8*)(Ob + gbase + k * 8) = *(const s16x8*)(tmp + k * 8);
}

extern "C" void kernel_launch(void* const* d_in, const int* in_sizes, int n_in,
                              void* d_out, int out_size, void* d_ws, size_t ws_size,
                              hipStream_t stream) {
  const float* x   = (const float*)d_in[0];
  const float* Wq  = (const float*)d_in[1];
  const float* Wkv = (const float*)d_in[2];
  const float* Wo  = (const float*)d_in[3];
  const float* bo  = (const float*)d_in[4];
  float* out = (float*)d_out;
  char* ws = (char*)d_ws;
  const size_t MB = 1048576;
  // ws map: wot 0..0.5M | wqkvt 0.5..2M | Qb 2..10M | Kb 10..18M | Vg 18..26M |
  //         Ob 26..34M | xbf 34..42M | pO 34..66M (overlaps dead xbf) | pM, pL
  u16* wot   = (u16*)(ws);
  u16* wqkvt = (u16*)(ws + MB / 2);
  u16* Qb    = (u16*)(ws + 2 * MB);
  u16* Kb    = (u16*)(ws + 10 * MB);
  u16* Vg    = (u16*)(ws + 18 * MB);
  u16* Ob    = (u16*)(ws + 26 * MB);
  u16* xbf   = (u16*)(ws + 34 * MB);
  u16* pO    = (u16*)(ws + 34 * MB);   // 32 MB: 16*64*4 chunks * 8KB (xbf dead by then)
  float* pM  = (float*)(ws + 66 * MB); // 1 MB
  float* pL  = (float*)(ws + 67 * MB); // 1 MB

  k_prep<<<4352, 256, 0, stream>>>(x, Wq, Wkv, Wo, xbf, wqkvt, wot);
  k_gemm_qkv<<<dim3(64, 12), 256, 0, stream>>>(xbf, wqkvt, Qb, Kb, Vg);
  k_attn_split<<<4096, 128, 0, stream>>>(Qb, Kb, Vg, pO, pM, pL);
  k_comb<<<1024, 128, 0, stream>>>(pO, pM, pL, Ob);
  k_gemm_out<<<dim3(64, 4), 256, 0, stream>>>(Ob, wot, bo, out);
}